// Round 2
// baseline (114.666 us; speedup 1.0000x reference)
//
#include <hip/hip_runtime.h>

#define M_DIM 64
#define K_DIM 8192
#define N_DIM 8192
#define QB 32
#define NT 64               // N columns per block (16 per wave)
#define KC 64               // K per stage (2 quant blocks)
#define SPLITS 8
#define KSPLIT (K_DIM / SPLITS)    // 1024
#define NSTAGE (KSPLIT / KC)       // 16

typedef __attribute__((ext_vector_type(8))) short short8;     // MFMA A/B frag (8 bf16)
typedef __attribute__((ext_vector_type(8))) unsigned short ushort8;
typedef __attribute__((ext_vector_type(4))) float f32x4;
typedef __attribute__((ext_vector_type(4))) unsigned int u32x4;

static_assert(NSTAGE * KC == KSPLIT, "split must tile");

// f32 -> bf16 round-to-nearest-even
__device__ __forceinline__ unsigned short f2bf(float f) {
    unsigned u = __builtin_bit_cast(unsigned, f);
    u += 0x7fffu + ((u >> 16) & 1u);
    return (unsigned short)(u >> 16);
}

// Rewrites the whole output with bias every call (d_out poisoned once, never
// re-poisoned between replays; qgemm atomicAdds on top of this).
__global__ __launch_bounds__(256) void bias_init(const float* __restrict__ bias,
                                                 float* __restrict__ out) {
    int i = (blockIdx.x * 256 + threadIdx.x) * 4;
    *(f32x4*)(out + i) = *(const f32x4*)(bias + (i & (N_DIM - 1)));
}

// One-shot x f32 -> bf16 into workspace (1 MB, stays L2-resident).
__global__ __launch_bounds__(256) void xcvt(const float* __restrict__ x,
                                            unsigned short* __restrict__ xb) {
    int i = (blockIdx.x * 256 + threadIdx.x) * 8;
    f32x4 a = *(const f32x4*)(x + i);
    f32x4 b = *(const f32x4*)(x + i + 4);
    ushort8 o;
    #pragma unroll
    for (int e = 0; e < 4; ++e) { o[e] = f2bf(a[e]); o[4 + e] = f2bf(b[e]); }
    *(ushort8*)(xb + i) = o;
}

// Barrier-free dequant GEMM: each wave owns 16 output columns, private LDS
// transpose tile, counted lgkmcnt/vmcnt waits only (no __syncthreads).
template <bool XBF>
__global__ __launch_bounds__(256, 4) void qgemm(
    const float* __restrict__ x,             // [M][K] f32 (fallback path)
    const unsigned short* __restrict__ xb,   // [M][K] bf16 (main path)
    const float* __restrict__ scales,        // [K/QB][N]
    const float* __restrict__ zeros,         // [K/QB][N]
    const int*   __restrict__ qw,            // [K][N], 0..255
    float*       __restrict__ out)           // [M][N]
{
    // Per-wave transposed weight tile [col16][k64], bf16. Row stride 72
    // shorts = 144 B (16B-aligned for b128; (36c+8q) spreads banks evenly).
    __shared__ unsigned short lq[4][16][72];

    const int tid  = threadIdx.x;
    const int lane = tid & 63;
    const int w    = tid >> 6;      // wave: owns cols [n0+16w, n0+16w+16)
    const int lr   = lane & 15;     // col-within-wave / m-row-within-16
    const int q    = lane >> 4;     // quarter

    const int n0  = blockIdx.x * NT;
    const int k0  = blockIdx.y * KSPLIT;
    const int col = n0 + 16 * w + lr;

    // Lane loads 16 consecutive k (= one half quant-block) of its column.
    const int*   qp = qw     + (size_t)(k0 + 16 * q) * N_DIM + col;
    const float* sp = scales + (size_t)((k0 >> 5) + (q >> 1)) * N_DIM + col;
    const float* zp = zeros  + (size_t)((k0 >> 5) + (q >> 1)) * N_DIM + col;

    // Prologue: stage-0 weight/scale loads
    int qv[16];
    #pragma unroll
    for (int j = 0; j < 16; ++j)
        qv[j] = __builtin_nontemporal_load(qp + (size_t)j * N_DIM);
    float sv = __builtin_nontemporal_load(sp);
    float zv = __builtin_nontemporal_load(zp);

    f32x4 acc[4];
    #pragma unroll
    for (int r = 0; r < 4; ++r) acc[r] = (f32x4){0.f, 0.f, 0.f, 0.f};

    for (int t = 0; t < NSTAGE; ++t) {
        const int kk = k0 + t * KC;

        // --- A-fragments straight from global (L2-resident x) ---
        short8 af[4][2];
        if (XBF) {
            const unsigned short* xp = xb + (size_t)lr * K_DIM + kk + 8 * q;
            #pragma unroll
            for (int r = 0; r < 4; ++r)
                #pragma unroll
                for (int c = 0; c < 2; ++c)
                    af[r][c] = *(const short8*)(xp + (size_t)r * 16 * K_DIM + 32 * c);
        } else {
            #pragma unroll
            for (int r = 0; r < 4; ++r)
                #pragma unroll
                for (int c = 0; c < 2; ++c) {
                    const float* xp = x + (size_t)(16 * r + lr) * K_DIM + kk + 32 * c + 8 * q;
                    f32x4 u = *(const f32x4*)xp;
                    f32x4 v = *(const f32x4*)(xp + 4);
                    #pragma unroll
                    for (int e = 0; e < 4; ++e) {
                        af[r][c][e]     = (short)f2bf(u[e]);
                        af[r][c][4 + e] = (short)f2bf(v[e]);
                    }
                }
        }

        // --- dequant stage-t regs -> 16 packed bf16 ---
        const float nz = -sv * zv;
        const float sc = sv;
        unsigned hh[8];
        #pragma unroll
        for (int j = 0; j < 8; ++j) {
            unsigned short h0 = f2bf(fmaf((float)qv[2 * j],     sc, nz));
            unsigned short h1 = f2bf(fmaf((float)qv[2 * j + 1], sc, nz));
            hh[j] = (unsigned)h0 | ((unsigned)h1 << 16);
        }

        // --- prefetch stage t+1 (stays in flight: no barrier anywhere) ---
        if (t + 1 < NSTAGE) {
            qp += (size_t)KC * N_DIM;
            #pragma unroll
            for (int j = 0; j < 16; ++j)
                qv[j] = __builtin_nontemporal_load(qp + (size_t)j * N_DIM);
            sp += 2 * N_DIM; zp += 2 * N_DIM;
            sv = __builtin_nontemporal_load(sp);
            zv = __builtin_nontemporal_load(zp);
        }

        // --- transpose through per-wave LDS tile (same-wave hazard only) ---
        *(u32x4*)&lq[w][lr][16 * q]     = (u32x4){hh[0], hh[1], hh[2], hh[3]};
        *(u32x4*)&lq[w][lr][16 * q + 8] = (u32x4){hh[4], hh[5], hh[6], hh[7]};

        short8 bf[2];
        #pragma unroll
        for (int c = 0; c < 2; ++c)
            bf[c] = *(const short8*)&lq[w][lr][32 * c + 8 * q];

        #pragma unroll
        for (int c = 0; c < 2; ++c)
            #pragma unroll
            for (int r = 0; r < 4; ++r)
                acc[r] = __builtin_amdgcn_mfma_f32_16x16x32_bf16(af[r][c], bf[c], acc[r], 0, 0, 0);
    }

    // --- epilogue: C layout col=lane&15, row=4*(lane>>4)+e ---
    #pragma unroll
    for (int r = 0; r < 4; ++r) {
        const int m = 16 * r + 4 * q;
        #pragma unroll
        for (int e = 0; e < 4; ++e)
            atomicAdd(out + (size_t)(m + e) * N_DIM + col, acc[r][e]);
    }
}

extern "C" void kernel_launch(void* const* d_in, const int* in_sizes, int n_in,
                              void* d_out, int out_size, void* d_ws, size_t ws_size,
                              hipStream_t stream) {
    const float* x      = (const float*)d_in[0];
    const float* scales = (const float*)d_in[1];
    const float* zeros  = (const float*)d_in[2];
    const float* bias   = (const float*)d_in[3];
    const int*   qw     = (const int*)d_in[4];
    float* out = (float*)d_out;
    unsigned short* xbf = (unsigned short*)d_ws;

    const bool use_xbf = ws_size >= (size_t)M_DIM * K_DIM * 2;

    bias_init<<<dim3((M_DIM * N_DIM) / 1024), 256, 0, stream>>>(bias, out);
    if (use_xbf) {
        xcvt<<<dim3((M_DIM * K_DIM) / 2048), 256, 0, stream>>>(x, xbf);
        qgemm<true><<<dim3(N_DIM / NT, SPLITS), 256, 0, stream>>>(x, xbf, scales, zeros, qw, out);
    } else {
        qgemm<false><<<dim3(N_DIM / NT, SPLITS), 256, 0, stream>>>(x, nullptr, scales, zeros, qw, out);
    }
}

// Round 3
// 85.931 us; speedup vs baseline: 1.3344x; 1.3344x over previous
//
#include <hip/hip_runtime.h>

#define M_DIM 64
#define K_DIM 8192
#define N_DIM 8192
#define QB 32
#define WN 64                      // cols per wave
#define NT 256                     // cols per block (4 waves)
#define KC 32                      // k per stage == QB
#define SPLITS 16
#define KSPLIT (K_DIM / SPLITS)    // 512
#define NSTAGE (KSPLIT / KC)       // 16 (even, required by ping-pong)

typedef __attribute__((ext_vector_type(8))) short short8;     // MFMA A/B frag
typedef __attribute__((ext_vector_type(8))) unsigned short ushort8;
typedef __attribute__((ext_vector_type(4))) float f32x4;
typedef __attribute__((ext_vector_type(4))) unsigned int u32x4;

static_assert(NSTAGE % 2 == 0 && NSTAGE * KC == KSPLIT, "tiling");

// f32 -> bf16 round-to-nearest-even
__device__ __forceinline__ unsigned short f2bf(float f) {
    unsigned u = __builtin_bit_cast(unsigned, f);
    u += 0x7fffu + ((u >> 16) & 1u);
    return (unsigned short)(u >> 16);
}

// Rewrites whole output with bias every call (d_out poisoned once, never
// re-poisoned between replays; qgemm atomicAdds on top).
__global__ __launch_bounds__(256) void bias_init(const float* __restrict__ bias,
                                                 float* __restrict__ out) {
    int i = (blockIdx.x * 256 + threadIdx.x) * 4;
    *(f32x4*)(out + i) = *(const f32x4*)(bias + (i & (N_DIM - 1)));
}

// One-shot x f32 -> bf16 into workspace (1 MB, L2-resident).
__global__ __launch_bounds__(256) void xcvt(const float* __restrict__ x,
                                            unsigned short* __restrict__ xb) {
    int i = (blockIdx.x * 256 + threadIdx.x) * 8;
    f32x4 a = *(const f32x4*)(x + i);
    f32x4 b = *(const f32x4*)(x + i + 4);
    ushort8 o;
    #pragma unroll
    for (int e = 0; e < 4; ++e) { o[e] = f2bf(a[e]); o[4 + e] = f2bf(b[e]); }
    *(ushort8*)(xb + i) = o;
}

// Barrier-free, wave-autonomous dequant GEMM.
// Wave owns 64 cols x 64 rows of C. Lane = column; weight loads are 256B
// fully-coalesced per instruction. Transpose via per-wave LDS tile with
// 16B-slot XOR swizzle. No __syncthreads -> no vmcnt(0) drain; ping-pong
// register sets give a counted-vmcnt software pipeline.
template <bool XBF>
__global__ __launch_bounds__(256, 2) void qgemm(
    const float* __restrict__ x,             // [M][K] f32 (fallback)
    const unsigned short* __restrict__ xb,   // [M][K] bf16 (main)
    const float* __restrict__ scales,        // [K/QB][N]
    const float* __restrict__ zeros,         // [K/QB][N]
    const int*   __restrict__ qw,            // [K][N], 0..255
    float*       __restrict__ out)           // [M][N]
{
    // Per-wave tile [col 64][k 32], bf16. Row stride 40 shorts = 80B
    // (16B-aligned for b128; 20 dwords -> 2-way-max bank aliasing with the
    // slot swizzle below).
    __shared__ unsigned short lq[4][WN][40];

    const int tid  = threadIdx.x;
    const int lane = tid & 63;
    const int w    = tid >> 6;
    const int q    = lane >> 4;      // k-group / C row-quarter
    const int lm   = lane & 15;

    const int n0  = blockIdx.x * NT + w * WN;   // wave's first column
    const int col = n0 + lane;                  // this lane's weight column
    const int k0  = blockIdx.y * KSPLIT;

    const int*   qp = qw     + (size_t)k0 * N_DIM + col;
    const float* sp = scales + (size_t)(k0 / QB) * N_DIM + col;
    const float* zp = zeros  + (size_t)(k0 / QB) * N_DIM + col;

    int   qvA[32], qvB[32];
    float svA, zvA, svB, zvB;

#define LOAD_STAGE(QV, SV, ZV, T)                                            \
    do {                                                                     \
        const int* _p = qp + (size_t)(T) * KC * N_DIM;                       \
        _Pragma("unroll")                                                    \
        for (int j = 0; j < 32; ++j)                                         \
            QV[j] = __builtin_nontemporal_load(_p + (size_t)j * N_DIM);      \
        SV = __builtin_nontemporal_load(sp + (size_t)(T) * N_DIM);           \
        ZV = __builtin_nontemporal_load(zp + (size_t)(T) * N_DIM);           \
    } while (0)

    // prologue: stage 0
    LOAD_STAGE(qvA, svA, zvA, 0);

    f32x4 acc[4][4];   // [colfrag][rowfrag]
    #pragma unroll
    for (int a = 0; a < 4; ++a)
        #pragma unroll
        for (int b = 0; b < 4; ++b) acc[a][b] = (f32x4){0.f, 0.f, 0.f, 0.f};

    const int wslot = (lane >> 3) & 3;   // write-side XOR key (per-row)

#define COMPUTE_STAGE(QV, SV, ZV, T)                                         \
    do {                                                                     \
        const float _nz = -(SV) * (ZV);                                      \
        unsigned hh[16];                                                     \
        _Pragma("unroll")                                                    \
        for (int j = 0; j < 16; ++j) {                                       \
            unsigned short h0 = f2bf(fmaf((float)QV[2 * j],     SV, _nz));   \
            unsigned short h1 = f2bf(fmaf((float)QV[2 * j + 1], SV, _nz));   \
            hh[j] = (unsigned)h0 | ((unsigned)h1 << 16);                     \
        }                                                                    \
        _Pragma("unroll")                                                    \
        for (int s = 0; s < 4; ++s) {                                        \
            const int s2 = s ^ wslot;                                        \
            *(u32x4*)&lq[w][lane][8 * s2] =                                  \
                (u32x4){hh[4 * s], hh[4 * s + 1], hh[4 * s + 2], hh[4 * s + 3]}; \
        }                                                                    \
        short8 bfr[4];                                                       \
        _Pragma("unroll")                                                    \
        for (int cf = 0; cf < 4; ++cf) {                                     \
            const int key = (2 * cf + (lm >> 3)) & 3;                        \
            bfr[cf] = *(const short8*)&lq[w][16 * cf + lm][8 * (q ^ key)];   \
        }                                                                    \
        short8 afr[4];                                                       \
        if (XBF) {                                                           \
            const unsigned short* _xp =                                      \
                xb + (size_t)lm * K_DIM + (k0 + (T) * KC) + 8 * q;           \
            _Pragma("unroll")                                                \
            for (int rf = 0; rf < 4; ++rf)                                   \
                afr[rf] = *(const short8*)(_xp + (size_t)rf * 16 * K_DIM);   \
        } else {                                                             \
            _Pragma("unroll")                                                \
            for (int rf = 0; rf < 4; ++rf) {                                 \
                const float* _xp = x + (size_t)(16 * rf + lm) * K_DIM        \
                                     + (k0 + (T) * KC) + 8 * q;              \
                f32x4 u = *(const f32x4*)_xp;                                \
                f32x4 v = *(const f32x4*)(_xp + 4);                          \
                _Pragma("unroll")                                            \
                for (int e = 0; e < 4; ++e) {                                \
                    afr[rf][e]     = (short)f2bf(u[e]);                      \
                    afr[rf][4 + e] = (short)f2bf(v[e]);                      \
                }                                                            \
            }                                                                \
        }                                                                    \
        _Pragma("unroll")                                                    \
        for (int cf = 0; cf < 4; ++cf)                                       \
            _Pragma("unroll")                                                \
            for (int rf = 0; rf < 4; ++rf)                                   \
                acc[cf][rf] = __builtin_amdgcn_mfma_f32_16x16x32_bf16(       \
                    afr[rf], bfr[cf], acc[cf][rf], 0, 0, 0);                 \
    } while (0)

    for (int t = 0; t < NSTAGE; t += 2) {
        LOAD_STAGE(qvB, svB, zvB, t + 1);      // in flight across compute(A)
        COMPUTE_STAGE(qvA, svA, zvA, t);
        if (t + 2 < NSTAGE)
            LOAD_STAGE(qvA, svA, zvA, t + 2);  // in flight across compute(B)
        COMPUTE_STAGE(qvB, svB, zvB, t + 1);
    }

#undef LOAD_STAGE
#undef COMPUTE_STAGE

    // epilogue: C layout col=lane&15, row=4*(lane>>4)+e (R1-validated)
    #pragma unroll
    for (int cf = 0; cf < 4; ++cf) {
        const int cn = n0 + 16 * cf + lm;
        #pragma unroll
        for (int rf = 0; rf < 4; ++rf) {
            const int m = 16 * rf + 4 * q;
            #pragma unroll
            for (int e = 0; e < 4; ++e)
                atomicAdd(out + (size_t)(m + e) * N_DIM + cn, acc[cf][rf][e]);
        }
    }
}

extern "C" void kernel_launch(void* const* d_in, const int* in_sizes, int n_in,
                              void* d_out, int out_size, void* d_ws, size_t ws_size,
                              hipStream_t stream) {
    const float* x      = (const float*)d_in[0];
    const float* scales = (const float*)d_in[1];
    const float* zeros  = (const float*)d_in[2];
    const float* bias   = (const float*)d_in[3];
    const int*   qw     = (const int*)d_in[4];
    float* out = (float*)d_out;
    unsigned short* xbf = (unsigned short*)d_ws;

    const bool use_xbf = ws_size >= (size_t)M_DIM * K_DIM * 2;

    bias_init<<<dim3((M_DIM * N_DIM) / 1024), 256, 0, stream>>>(bias, out);
    if (use_xbf) {
        xcvt<<<dim3((M_DIM * K_DIM) / 2048), 256, 0, stream>>>(x, xbf);
        qgemm<true><<<dim3(N_DIM / NT, SPLITS), 256, 0, stream>>>(x, xbf, scales, zeros, qw, out);
    } else {
        qgemm<false><<<dim3(N_DIM / NT, SPLITS), 256, 0, stream>>>(x, nullptr, scales, zeros, qw, out);
    }
}

// Round 4
// 80.513 us; speedup vs baseline: 1.4242x; 1.0673x over previous
//
#include <hip/hip_runtime.h>

#define M_DIM 64
#define K_DIM 8192
#define N_DIM 8192
#define QB 32
#define WN 64                      // cols per wave
#define NT 256                     // cols per block (4 waves)
#define KC 32                      // k per stage == QB
#define SPLITS 16
#define KSPLIT (K_DIM / SPLITS)    // 512
#define NSTAGE (KSPLIT / KC)       // 16 (even, required by ping-pong)

typedef __attribute__((ext_vector_type(8))) short short8;     // MFMA A/B frag
typedef __attribute__((ext_vector_type(8))) unsigned short ushort8;
typedef __attribute__((ext_vector_type(4))) float f32x4;
typedef __attribute__((ext_vector_type(4))) unsigned int u32x4;

static_assert(NSTAGE % 2 == 0 && NSTAGE * KC == KSPLIT, "tiling");

// f32 -> bf16 round-to-nearest-even
__device__ __forceinline__ unsigned short f2bf(float f) {
    unsigned u = __builtin_bit_cast(unsigned, f);
    u += 0x7fffu + ((u >> 16) & 1u);
    return (unsigned short)(u >> 16);
}

// Rewrites whole output with bias every call (d_out poisoned once, never
// re-poisoned between replays; qgemm atomicAdds on top).
__global__ __launch_bounds__(256) void bias_init(const float* __restrict__ bias,
                                                 float* __restrict__ out) {
    int i = (blockIdx.x * 256 + threadIdx.x) * 4;
    *(f32x4*)(out + i) = *(const f32x4*)(bias + (i & (N_DIM - 1)));
}

// One-shot x f32 -> bf16 into workspace (1 MB, L2-resident).
__global__ __launch_bounds__(256) void xcvt(const float* __restrict__ x,
                                            unsigned short* __restrict__ xb) {
    int i = (blockIdx.x * 256 + threadIdx.x) * 8;
    f32x4 a = *(const f32x4*)(x + i);
    f32x4 b = *(const f32x4*)(x + i + 4);
    ushort8 o;
    #pragma unroll
    for (int e = 0; e < 4; ++e) { o[e] = f2bf(a[e]); o[4 + e] = f2bf(b[e]); }
    *(ushort8*)(xb + i) = o;
}

// Barrier-free, wave-autonomous dequant GEMM.
// Key rule (R3 lesson): COMPUTE_STAGE touches NO global memory. vmcnt is a
// FIFO — any global load consumed inside compute would force draining the
// weight prefetch issued before it. All vmem (weights + scale/zero + x
// A-frags) is issued in LOAD_STAGE, one full compute-stage ahead.
template <bool XBF>
__global__ __launch_bounds__(256, 2) void qgemm(
    const float* __restrict__ x,             // [M][K] f32 (fallback)
    const unsigned short* __restrict__ xb,   // [M][K] bf16 (main)
    const float* __restrict__ scales,        // [K/QB][N]
    const float* __restrict__ zeros,         // [K/QB][N]
    const int*   __restrict__ qw,            // [K][N], 0..255
    float*       __restrict__ out)           // [M][N]
{
    // Per-wave tile [col 64][k 32], bf16. Row stride 40 shorts = 80B
    // (16B-aligned for b128; slot-XOR swizzle keeps aliasing <=2-way).
    __shared__ unsigned short lq[4][WN][40];

    const int tid  = threadIdx.x;
    const int lane = tid & 63;
    const int w    = tid >> 6;
    const int q    = lane >> 4;      // k-slot / C row-quarter
    const int lm   = lane & 15;

    const int n0  = blockIdx.x * NT + w * WN;   // wave's first column
    const int col = n0 + lane;                  // this lane's weight column
    const int k0  = blockIdx.y * KSPLIT;

    const int*   qp = qw     + (size_t)k0 * N_DIM + col;
    const float* sp = scales + (size_t)(k0 / QB) * N_DIM + col;
    const float* zp = zeros  + (size_t)(k0 / QB) * N_DIM + col;

    int   qvA[32], qvB[32];
    float svA, zvA, svB, zvB;
    short8 afrA[4], afrB[4];

#define LOAD_STAGE(QV, SV, ZV, AF, T)                                        \
    do {                                                                     \
        const int* _p = qp + (size_t)(T) * KC * N_DIM;                       \
        _Pragma("unroll")                                                    \
        for (int j = 0; j < 32; ++j)                                         \
            QV[j] = __builtin_nontemporal_load(_p + (size_t)j * N_DIM);      \
        SV = __builtin_nontemporal_load(sp + (size_t)(T) * N_DIM);           \
        ZV = __builtin_nontemporal_load(zp + (size_t)(T) * N_DIM);           \
        if (XBF) {                                                           \
            const unsigned short* _xp = xb + (size_t)lm * K_DIM              \
                                           + (k0 + (T) * KC) + 8 * q;        \
            _Pragma("unroll")                                                \
            for (int rf = 0; rf < 4; ++rf)                                   \
                AF[rf] = *(const short8*)(_xp + (size_t)rf * 16 * K_DIM);    \
        } else {                                                             \
            _Pragma("unroll")                                                \
            for (int rf = 0; rf < 4; ++rf) {                                 \
                const float* _xp = x + (size_t)(16 * rf + lm) * K_DIM        \
                                     + (k0 + (T) * KC) + 8 * q;              \
                f32x4 u = *(const f32x4*)_xp;                                \
                f32x4 v = *(const f32x4*)(_xp + 4);                          \
                _Pragma("unroll")                                            \
                for (int e = 0; e < 4; ++e) {                                \
                    AF[rf][e]     = (short)f2bf(u[e]);                       \
                    AF[rf][4 + e] = (short)f2bf(v[e]);                       \
                }                                                            \
            }                                                                \
        }                                                                    \
    } while (0)

    // prologue: stage 0
    LOAD_STAGE(qvA, svA, zvA, afrA, 0);

    f32x4 acc[4][4];   // [colfrag][rowfrag]
    #pragma unroll
    for (int a = 0; a < 4; ++a)
        #pragma unroll
        for (int b = 0; b < 4; ++b) acc[a][b] = (f32x4){0.f, 0.f, 0.f, 0.f};

    const int wslot = (lane >> 3) & 3;   // write-side XOR key (per-row)

#define COMPUTE_STAGE(QV, SV, ZV, AF)                                        \
    do {                                                                     \
        const float _nz = -(SV) * (ZV);                                      \
        unsigned hh[16];                                                     \
        _Pragma("unroll")                                                    \
        for (int j = 0; j < 16; ++j) {                                       \
            unsigned short h0 = f2bf(fmaf((float)QV[2 * j],     SV, _nz));   \
            unsigned short h1 = f2bf(fmaf((float)QV[2 * j + 1], SV, _nz));   \
            hh[j] = (unsigned)h0 | ((unsigned)h1 << 16);                     \
        }                                                                    \
        _Pragma("unroll")                                                    \
        for (int s = 0; s < 4; ++s) {                                        \
            const int s2 = s ^ wslot;                                        \
            *(u32x4*)&lq[w][lane][8 * s2] =                                  \
                (u32x4){hh[4 * s], hh[4 * s + 1], hh[4 * s + 2], hh[4 * s + 3]}; \
        }                                                                    \
        short8 bfr[4];                                                       \
        _Pragma("unroll")                                                    \
        for (int cf = 0; cf < 4; ++cf) {                                     \
            const int key = (2 * cf + (lm >> 3)) & 3;                        \
            bfr[cf] = *(const short8*)&lq[w][16 * cf + lm][8 * (q ^ key)];   \
        }                                                                    \
        _Pragma("unroll")                                                    \
        for (int cf = 0; cf < 4; ++cf)                                       \
            _Pragma("unroll")                                                \
            for (int rf = 0; rf < 4; ++rf)                                   \
                acc[cf][rf] = __builtin_amdgcn_mfma_f32_16x16x32_bf16(       \
                    AF[rf], bfr[cf], acc[cf][rf], 0, 0, 0);                  \
    } while (0)

    for (int t = 0; t < NSTAGE; t += 2) {
        LOAD_STAGE(qvB, svB, zvB, afrB, t + 1);   // in flight across compute(A)
        COMPUTE_STAGE(qvA, svA, zvA, afrA);
        if (t + 2 < NSTAGE)
            LOAD_STAGE(qvA, svA, zvA, afrA, t + 2); // in flight across compute(B)
        COMPUTE_STAGE(qvB, svB, zvB, afrB);
    }

#undef LOAD_STAGE
#undef COMPUTE_STAGE

    // epilogue: C layout col=lane&15, row=4*(lane>>4)+e (R1-validated)
    #pragma unroll
    for (int cf = 0; cf < 4; ++cf) {
        const int cn = n0 + 16 * cf + lm;
        #pragma unroll
        for (int rf = 0; rf < 4; ++rf) {
            const int m = 16 * rf + 4 * q;
            #pragma unroll
            for (int e = 0; e < 4; ++e)
                atomicAdd(out + (size_t)(m + e) * N_DIM + cn, acc[cf][rf][e]);
        }
    }
}

extern "C" void kernel_launch(void* const* d_in, const int* in_sizes, int n_in,
                              void* d_out, int out_size, void* d_ws, size_t ws_size,
                              hipStream_t stream) {
    const float* x      = (const float*)d_in[0];
    const float* scales = (const float*)d_in[1];
    const float* zeros  = (const float*)d_in[2];
    const float* bias   = (const float*)d_in[3];
    const int*   qw     = (const int*)d_in[4];
    float* out = (float*)d_out;
    unsigned short* xbf = (unsigned short*)d_ws;

    const bool use_xbf = ws_size >= (size_t)M_DIM * K_DIM * 2;

    bias_init<<<dim3((M_DIM * N_DIM) / 1024), 256, 0, stream>>>(bias, out);
    if (use_xbf) {
        xcvt<<<dim3((M_DIM * K_DIM) / 2048), 256, 0, stream>>>(x, xbf);
        qgemm<true><<<dim3(N_DIM / NT, SPLITS), 256, 0, stream>>>(x, xbf, scales, zeros, qw, out);
    } else {
        qgemm<false><<<dim3(N_DIM / NT, SPLITS), 256, 0, stream>>>(x, nullptr, scales, zeros, qw, out);
    }
}